// Round 1
// baseline (555.803 us; speedup 1.0000x reference)
//
#include <hip/hip_runtime.h>

#define NEGV -10000.0f
#define BB 1024
#define TT 512
#define KK 64

// ---------------------------------------------------------------------------
// K0: trans = log_softmax(A + inv_mask*NEG, axis=-1); also store transpose.
// One block per row i, 64 lanes = columns j.
// ---------------------------------------------------------------------------
__global__ __launch_bounds__(64)
void trans_kernel(const float* __restrict__ A, const int* __restrict__ inv,
                  float* __restrict__ trans, float* __restrict__ transT)
{
    const int i = blockIdx.x, j = threadIdx.x;
    float x = A[i * KK + j] + (inv[i * KK + j] ? NEGV : 0.0f);
    float m = x;
    #pragma unroll
    for (int o = 32; o > 0; o >>= 1) m = fmaxf(m, __shfl_xor(m, o));
    float e = expf(x - m);
    float s = e;
    #pragma unroll
    for (int o = 32; o > 0; o >>= 1) s += __shfl_xor(s, o);
    float t = (x - m) - logf(s);
    trans[i * KK + j]  = t;
    transT[j * KK + i] = t;
}

// ---------------------------------------------------------------------------
// K1: fused Viterbi forward + backtrack. One wave (64 threads) per batch row.
// lane = tag index j. trans column T[.][lane] lives in 64 VGPRs.
// alpha history is stored IN PLACE over the consumed unary rows; backward
// recomputes the argmax along the surviving path only (ballot+ffs == first-
// index argmax, bitwise-identical adds to the forward).
// ---------------------------------------------------------------------------
__global__ __launch_bounds__(64)
void viterbi_kernel(float* __restrict__ unary, const int* __restrict__ lengths,
                    const float* __restrict__ trans, const float* __restrict__ transT,
                    int* __restrict__ out)
{
    const int lane = threadIdx.x;
    const int b = blockIdx.x;

    __shared__ float  sT[KK * KK];   // transT rows: sT[tag*64 + i], row-contiguous gather
    __shared__ float4 sA4[2][16];    // alpha broadcast buffer (double-buffered)

    #pragma unroll 4
    for (int r = 0; r < KK; ++r) sT[r * KK + lane] = transT[r * KK + lane];

    float Treg[KK];                  // Treg[i] = trans[i][lane]
    #pragma unroll
    for (int i = 0; i < KK; ++i) Treg[i] = trans[i * KK + lane];

    const int len = lengths[b];                      // 1..512, wave-uniform
    float* urow = unary + (long)b * (TT * KK);
    int*   orow = out + b * TT;

    // alpha_0 = GO frame: 0 at tag GO=1, NEG elsewhere
    float alpha = (lane == 1) ? 0.0f : NEGV;
    float alpha_prev = 0.0f;                          // alpha_{t-2}
    float u_cur = urow[lane];                         // unary row 0 (for t=1)
    int p = 0;

    __syncthreads();

    for (int t = 1; t <= len; ++t) {
        // broadcast alpha_{t-1} through LDS
        ((float*)&sA4[p][0])[lane] = alpha;
        __builtin_amdgcn_wave_barrier();
        // store alpha history row t-2 (its unary value was consumed at iter t-1)
        if (t >= 3) urow[(t - 2) * KK + lane] = alpha_prev;
        // prefetch next unary row (clamped; dead value on last iter)
        int tn = t < TT ? t : TT - 1;
        float u_next = urow[tn * KK + lane];

        float best0 = -1e30f, best1 = -1e30f;
        #pragma unroll
        for (int i4 = 0; i4 < 16; ++i4) {
            float4 a4 = sA4[p][i4];                   // same-address broadcast read
            best0 = fmaxf(fmaxf(best0, a4.x + Treg[4 * i4 + 0]), a4.y + Treg[4 * i4 + 1]);
            best1 = fmaxf(fmaxf(best1, a4.z + Treg[4 * i4 + 2]), a4.w + Treg[4 * i4 + 3]);
        }
        alpha_prev = alpha;
        alpha = fmaxf(best0, best1) + u_cur;          // consumes u (forces vmcnt wait)
        u_cur = u_next;
        p ^= 1;
    }
    if (len >= 2) urow[(len - 1) * KK + lane] = alpha_prev;   // history row len-1

    // last = argmax_j alpha_final (first index on ties, like jnp.argmax)
    float m = alpha;
    #pragma unroll
    for (int o = 32; o > 0; o >>= 1) m = fmaxf(m, __shfl_xor(m, o));
    unsigned long long msk = __ballot(alpha == m);
    int last = __ffsll(msk) - 1;

    // out[jj] = last for jj >= len-1 (tags carry beyond sequence end)
    for (int jj = len - 1 + lane; jj < TT; jj += 64) orow[jj] = last;

    __builtin_amdgcn_s_waitcnt(0);   // drain history stores before reading back

    // backtrack: for t = len..2: prev = argmax_i(alpha_{t-1}[i] + T[i][tag]); out[t-2] = prev
    int tag = last;
    float a0 = (len >= 2) ? urow[(len - 1) * KK + lane] : 0.0f;   // row t-1 for t=len
    float a1 = (len >= 3) ? urow[(len - 2) * KK + lane] : 0.0f;   // depth-2 prefetch
    for (int t = len; t >= 2; --t) {
        float v = a0 + sT[tag * KK + lane];           // bitwise same add as forward
        a0 = a1;
        int r = t - 3;
        a1 = (r >= 1) ? urow[r * KK + lane] : 0.0f;
        float mm = v;
        #pragma unroll
        for (int o = 32; o > 0; o >>= 1) mm = fmaxf(mm, __shfl_xor(mm, o));
        unsigned long long em = __ballot(v == mm);
        int prev = __ffsll(em) - 1;                   // first i hitting the max
        if (lane == 0) orow[t - 2] = prev;
        tag = prev;
    }
}

extern "C" void kernel_launch(void* const* d_in, const int* in_sizes, int n_in,
                              void* d_out, int out_size, void* d_ws, size_t ws_size,
                              hipStream_t stream)
{
    float*       unary   = (float*)d_in[0];          // clobbered in-kernel; harness restores
    const int*   lengths = (const int*)d_in[1];
    const int*   inv     = (const int*)d_in[2];
    const float* A       = (const float*)d_in[3];
    int*         out     = (int*)d_out;

    float* trans  = (float*)d_ws;                    // 4096 floats
    float* transT = trans + KK * KK;                 // 4096 floats

    trans_kernel<<<KK, KK, 0, stream>>>(A, inv, trans, transT);
    viterbi_kernel<<<BB, KK, 0, stream>>>(unary, lengths, trans, transT, out);
}